// Round 1
// baseline (110.034 us; speedup 1.0000x reference)
//
#include <hip/hip_runtime.h>

#define B_SZ  64
#define N_SZ  512
#define K_SZ  16
#define EMB   128
#define R_TOT (B_SZ * N_SZ)   // 32768 rows

// C[r][c] = (RELU_A ? relu(A) : A)[r][:] dot W[:][c]  (+ bias[c] if BIAS)
// A: [R,128] f32, W: [128,128] f32 row-major, out: [R,128]
template<bool RELU_A, bool BIAS>
__global__ __launch_bounds__(256) void gemm128(const float* __restrict__ A,
                                               const float* __restrict__ W,
                                               const float* __restrict__ bias,
                                               float* __restrict__ out)
{
    __shared__ float sA[64][132];     // +4 pad keeps float4 alignment, breaks bank stride
    __shared__ float sW[128][128];
    const int tid = threadIdx.x;
    const int block_row = blockIdx.x * 64;

    // stage W: 16384 floats, coalesced float4
    {
        const float4* Wv = (const float4*)W;
        float4* sWv = (float4*)&sW[0][0];
        for (int i = tid; i < 4096; i += 256) sWv[i] = Wv[i];
    }
    // stage A tile: 64 rows x 128, optional relu on load
    for (int i = tid; i < 2048; i += 256) {
        int r  = i >> 5;
        int c4 = i & 31;
        float4 v = ((const float4*)(A + (size_t)(block_row + r) * EMB))[c4];
        if (RELU_A) {
            v.x = fmaxf(v.x, 0.f); v.y = fmaxf(v.y, 0.f);
            v.z = fmaxf(v.z, 0.f); v.w = fmaxf(v.w, 0.f);
        }
        *(float4*)&sA[r][c4 * 4] = v;
    }
    __syncthreads();

    const int tx = tid & 31;   // cols 4*tx .. 4*tx+3
    const int ty = tid >> 5;   // rows ty, ty+8, ..., ty+56
    float acc[8][4];
    #pragma unroll
    for (int j = 0; j < 8; ++j)
        acc[j][0] = acc[j][1] = acc[j][2] = acc[j][3] = 0.f;

    #pragma unroll 4
    for (int f4 = 0; f4 < 32; ++f4) {
        float4 w0 = *(const float4*)&sW[4*f4 + 0][tx*4];
        float4 w1 = *(const float4*)&sW[4*f4 + 1][tx*4];
        float4 w2 = *(const float4*)&sW[4*f4 + 2][tx*4];
        float4 w3 = *(const float4*)&sW[4*f4 + 3][tx*4];
        #pragma unroll
        for (int j = 0; j < 8; ++j) {
            float4 a = *(const float4*)&sA[ty + 8*j][4*f4];
            acc[j][0] += a.x*w0.x + a.y*w1.x + a.z*w2.x + a.w*w3.x;
            acc[j][1] += a.x*w0.y + a.y*w1.y + a.z*w2.y + a.w*w3.y;
            acc[j][2] += a.x*w0.z + a.y*w1.z + a.z*w2.z + a.w*w3.z;
            acc[j][3] += a.x*w0.w + a.y*w1.w + a.z*w2.w + a.w*w3.w;
        }
    }

    #pragma unroll
    for (int j = 0; j < 8; ++j) {
        int row = block_row + ty + 8*j;
        float4 o = make_float4(acc[j][0], acc[j][1], acc[j][2], acc[j][3]);
        if (BIAS) {
            float4 bv = *(const float4*)(bias + tx*4);
            o.x += bv.x; o.y += bv.y; o.z += bv.z; o.w += bv.w;
        }
        *(float4*)(out + (size_t)row * EMB + tx*4) = o;
    }
}

// Per (b,n): agg_e = mean_k Y[b, nb[b,n,k], e]; e2 = relu(X[b,n,e] + agg_e);
// accumulate mask[b,n]*e2 into pooled[b][e].
// grid: B*16 blocks, 256 threads = 2 groups x 128 lanes; each group does 16 n's.
__global__ __launch_bounds__(256) void gather_pool(const float* __restrict__ X,
                                                   const float* __restrict__ Y,
                                                   const int*   __restrict__ nb,
                                                   const float* __restrict__ mask,
                                                   float* __restrict__ pooled)
{
    const int b      = blockIdx.x >> 4;          // 16 blocks per batch
    const int nbase  = (blockIdx.x & 15) * 32;   // 32 n's per block
    const int g      = threadIdx.x >> 7;         // group 0/1
    const int e      = threadIdx.x & 127;
    const float* Yb  = Y + (size_t)b * N_SZ * EMB;
    float lsum = 0.f;

    for (int nn = 0; nn < 16; ++nn) {
        const int n = nbase + nn*2 + g;
        const int* idx = nb + ((size_t)b * N_SZ + n) * K_SZ;
        float aggv = 0.f;
        #pragma unroll
        for (int k = 0; k < K_SZ; ++k)
            aggv += Yb[(size_t)idx[k] * EMB + e];
        float x = X[((size_t)b * N_SZ + n) * EMB + e];
        float v = x + aggv * (1.f / K_SZ);
        v = fmaxf(v, 0.f);
        lsum += v * mask[b * N_SZ + n];
    }
    atomicAdd(&pooled[b * EMB + e], lsum);
}

// out[b][e] = sum_f pooled[b][f] * W2[f][e]
__global__ __launch_bounds__(128) void final_mm(const float* __restrict__ pooled,
                                                const float* __restrict__ W2,
                                                float* __restrict__ out)
{
    __shared__ float sp[EMB];
    const int b = blockIdx.x, e = threadIdx.x;
    sp[e] = pooled[b * EMB + e];
    __syncthreads();
    float acc = 0.f;
    for (int f = 0; f < EMB; ++f)
        acc += sp[f] * W2[f * EMB + e];
    out[b * EMB + e] = acc;
}

extern "C" void kernel_launch(void* const* d_in, const int* in_sizes, int n_in,
                              void* d_out, int out_size, void* d_ws, size_t ws_size,
                              hipStream_t stream)
{
    const float* word  = (const float*)d_in[0];
    const int*   nb    = (const int*)  d_in[1];
    const float* mask  = (const float*)d_in[2];
    const float* W_enc = (const float*)d_in[3];
    const float* b_enc = (const float*)d_in[4];
    const float* W2    = (const float*)d_in[5];
    float* out = (float*)d_out;

    float* X      = (float*)d_ws;                  // [32768,128] pre-relu iter-1 logits
    float* Y      = X + (size_t)R_TOT * EMB;       // [32768,128] relu(X) @ W_bot
    float* pooled = Y + (size_t)R_TOT * EMB;       // [64,128]

    hipMemsetAsync(pooled, 0, B_SZ * EMB * sizeof(float), stream);

    // X = word @ W_enc[0:128] + b_enc   (no relu on store; consumers relu on read)
    gemm128<false, true ><<<R_TOT / 64, 256, 0, stream>>>(word, W_enc, b_enc, X);
    // Y = relu(X) @ W_enc[128:256]
    gemm128<true,  false><<<R_TOT / 64, 256, 0, stream>>>(X, W_enc + 128 * EMB, nullptr, Y);

    gather_pool<<<B_SZ * 16, 256, 0, stream>>>(X, Y, nb, mask, pooled);
    final_mm<<<B_SZ, 128, 0, stream>>>(pooled, W2, out);
}

// Round 3
// 45.305 us; speedup vs baseline: 2.4287x; 2.4287x over previous
//
#include <hip/hip_runtime.h>
#include <hip/hip_bf16.h>

#define B_SZ  64
#define N_SZ  512
#define K_SZ  16
#define EMB   128
#define R_TOT (B_SZ * N_SZ)   // 32768 rows

typedef __attribute__((ext_vector_type(8))) short bf16x8;
typedef __attribute__((ext_vector_type(4))) float f32x4;

static __device__ __forceinline__ unsigned short f2bf(float x) {
    __hip_bfloat16 h = __float2bfloat16(x);   // RNE
    return *reinterpret_cast<unsigned short*>(&h);
}
static __device__ __forceinline__ float bf2f(unsigned short u) {
    union { unsigned int u32; float f; } c; c.u32 = ((unsigned int)u) << 16; return c.f;
}

// W_enc [256][128] f32 -> wt[2][128][128] bf16, transposed: wt[half][e][f] = W_enc[half*128+f][e]
__global__ __launch_bounds__(256) void prep_w(const float* __restrict__ W_enc,
                                              unsigned short* __restrict__ wt)
{
    __shared__ float s[16][128];
    const int tid = threadIdx.x;
    const int f0 = blockIdx.x * 16;          // 16 blocks cover 256 f-rows
    for (int i = tid; i < 2048; i += 256) {
        int r = i >> 7, c = i & 127;
        s[r][c] = W_enc[(f0 + r) * EMB + c];
    }
    __syncthreads();
    if (tid < 128) {
        const int e = tid;
        unsigned short* dst = wt + ((f0 >= 128) ? (EMB * EMB) : 0) + e * EMB + (f0 & 127);
        for (int j = 0; j < 16; j += 2) {
            unsigned int v = (unsigned int)f2bf(s[j][e]) | ((unsigned int)f2bf(s[j + 1][e]) << 16);
            *(unsigned int*)(dst + j) = v;
        }
    }
}

// Fused: X = word@Wtop + bias (store bf16, pre-relu); Y = relu(X)@Wbot (store bf16)
// block = 64 rows, 256 threads (4 waves). Wave w owns cols [w*32, w*32+32).
__global__ __launch_bounds__(256) void dual_gemm(const float* __restrict__ word,
                                                 const unsigned short* __restrict__ wt,
                                                 const float* __restrict__ bias,
                                                 unsigned short* __restrict__ Xb,
                                                 unsigned short* __restrict__ Yb)
{
    __shared__ unsigned short sA[64][EMB];       // 16 KB, A-tile (bf16)
    __shared__ unsigned short sW[2][EMB][EMB];   // 64 KB, both W halves, [e][f] layout
    const int tid = threadIdx.x;
    const int block_row = blockIdx.x * 64;

    {   // stage both W halves: 64 KB = 4096 x uint4
        const uint4* src = (const uint4*)wt;
        uint4* dst = (uint4*)&sW[0][0][0];
        for (int i = tid; i < 4096; i += 256) dst[i] = src[i];
    }
    for (int i = tid; i < 2048; i += 256) {      // A tile f32 -> bf16
        int r = i >> 5, c4 = i & 31;
        float4 v = ((const float4*)(word + (size_t)(block_row + r) * EMB))[c4];
        unsigned short o[4] = { f2bf(v.x), f2bf(v.y), f2bf(v.z), f2bf(v.w) };
        *(uint2*)&sA[r][c4 * 4] = *(uint2*)o;
    }
    __syncthreads();

    const int lane  = tid & 63;
    const int w     = tid >> 6;
    const int l15   = lane & 15;
    const int g     = lane >> 4;                 // 0..3
    const int ncol0 = w * 32;

    f32x4 acc[4][2];
    #pragma unroll
    for (int mb = 0; mb < 4; ++mb)
        #pragma unroll
        for (int nb = 0; nb < 2; ++nb)
            acc[mb][nb] = (f32x4){0.f, 0.f, 0.f, 0.f};

    // ---- GEMM1: sA @ sW[0] ----
    #pragma unroll
    for (int ks = 0; ks < 4; ++ks) {
        bf16x8 a[4], b[2];
        #pragma unroll
        for (int mb = 0; mb < 4; ++mb)
            a[mb] = *(const bf16x8*)&sA[mb * 16 + l15][ks * 32 + g * 8];
        #pragma unroll
        for (int nb = 0; nb < 2; ++nb)
            b[nb] = *(const bf16x8*)&sW[0][ncol0 + nb * 16 + l15][ks * 32 + g * 8];
        #pragma unroll
        for (int mb = 0; mb < 4; ++mb)
            #pragma unroll
            for (int nb = 0; nb < 2; ++nb)
                acc[mb][nb] = __builtin_amdgcn_mfma_f32_16x16x32_bf16(a[mb], b[nb], acc[mb][nb], 0, 0, 0);
    }
    __syncthreads();   // everyone done READING sA before we overwrite it

    // epilogue 1: X = acc + bias; store Xb (pre-relu); relu into sA for GEMM2
    #pragma unroll
    for (int mb = 0; mb < 4; ++mb) {
        #pragma unroll
        for (int nb = 0; nb < 2; ++nb) {
            const int col = ncol0 + nb * 16 + l15;
            const float bv = bias[col];
            #pragma unroll
            for (int r = 0; r < 4; ++r) {
                const int row_l = mb * 16 + g * 4 + r;
                float x = acc[mb][nb][r] + bv;
                Xb[(size_t)(block_row + row_l) * EMB + col] = f2bf(x);
                sA[row_l][col] = f2bf(fmaxf(x, 0.f));
            }
            acc[mb][nb] = (f32x4){0.f, 0.f, 0.f, 0.f};
        }
    }
    __syncthreads();

    // ---- GEMM2: relu(X) @ sW[1] ----
    #pragma unroll
    for (int ks = 0; ks < 4; ++ks) {
        bf16x8 a[4], b[2];
        #pragma unroll
        for (int mb = 0; mb < 4; ++mb)
            a[mb] = *(const bf16x8*)&sA[mb * 16 + l15][ks * 32 + g * 8];
        #pragma unroll
        for (int nb = 0; nb < 2; ++nb)
            b[nb] = *(const bf16x8*)&sW[1][ncol0 + nb * 16 + l15][ks * 32 + g * 8];
        #pragma unroll
        for (int mb = 0; mb < 4; ++mb)
            #pragma unroll
            for (int nb = 0; nb < 2; ++nb)
                acc[mb][nb] = __builtin_amdgcn_mfma_f32_16x16x32_bf16(a[mb], b[nb], acc[mb][nb], 0, 0, 0);
    }
    #pragma unroll
    for (int mb = 0; mb < 4; ++mb)
        #pragma unroll
        for (int nb = 0; nb < 2; ++nb) {
            const int col = ncol0 + nb * 16 + l15;
            #pragma unroll
            for (int r = 0; r < 4; ++r) {
                const int row_l = mb * 16 + g * 4 + r;
                Yb[(size_t)(block_row + row_l) * EMB + col] = f2bf(acc[mb][nb][r]);
            }
        }
}

// partial[b][chunk][g][e] = sum over group-g's 8 n's of mask * relu(X + mean_k Y[nb])
// XCD swizzle: all 16 chunks of batch b land on XCD b&7.
__global__ __launch_bounds__(256) void gather_pool(const unsigned short* __restrict__ Xb,
                                                   const unsigned short* __restrict__ Yb,
                                                   const int*   __restrict__ nbr,
                                                   const float* __restrict__ mask,
                                                   float* __restrict__ partial)
{
    const int bid   = blockIdx.x;
    const int xcd   = bid & 7;
    const int rest  = bid >> 3;
    const int chunk = rest & 15;
    const int b     = (rest >> 4) * 8 + xcd;
    const int g     = threadIdx.x >> 6;        // 4 groups of 64 lanes
    const int lane  = threadIdx.x & 63;
    const int e0    = lane * 2;
    const unsigned short* Yb_b = Yb + (size_t)b * N_SZ * EMB;

    float s0 = 0.f, s1 = 0.f;
    for (int nn = 0; nn < 8; ++nn) {
        const int n = chunk * 32 + g * 8 + nn;
        const long base = (long)b * N_SZ + n;
        const int* idx = nbr + base * K_SZ;
        int id[K_SZ];
        #pragma unroll
        for (int k = 0; k < K_SZ; ++k) id[k] = idx[k];
        float a0 = 0.f, a1 = 0.f;
        #pragma unroll
        for (int k = 0; k < K_SZ; ++k) {
            unsigned int v = *(const unsigned int*)(Yb_b + (size_t)id[k] * EMB + e0);
            a0 += bf2f((unsigned short)v);
            a1 += bf2f((unsigned short)(v >> 16));
        }
        unsigned int xv = *(const unsigned int*)(Xb + base * EMB + e0);
        const float m = mask[base];
        s0 += fmaxf(bf2f((unsigned short)xv)         + a0 * 0.0625f, 0.f) * m;
        s1 += fmaxf(bf2f((unsigned short)(xv >> 16)) + a1 * 0.0625f, 0.f) * m;
    }
    // per-group slot: no cross-group race (Round-2 bug was 4 groups -> same slot)
    float2 o = { s0, s1 };
    *(float2*)&partial[(((size_t)b * 16 + chunk) * 4 + g) * EMB + e0] = o;
}

// out[b][e] = (sum over 64 partials of partial[b][c][:]) @ W2
__global__ __launch_bounds__(128) void final_mm(const float* __restrict__ partial,
                                                const float* __restrict__ W2,
                                                float* __restrict__ out)
{
    __shared__ float sp[EMB];
    const int b = blockIdx.x, e = threadIdx.x;
    float s = 0.f;
    #pragma unroll
    for (int c = 0; c < 64; ++c) s += partial[((size_t)b * 64 + c) * EMB + e];
    sp[e] = s;
    __syncthreads();
    float acc = 0.f;
    #pragma unroll 8
    for (int f = 0; f < EMB; ++f) acc += sp[f] * W2[f * EMB + e];
    out[b * EMB + e] = acc;
}

extern "C" void kernel_launch(void* const* d_in, const int* in_sizes, int n_in,
                              void* d_out, int out_size, void* d_ws, size_t ws_size,
                              hipStream_t stream)
{
    const float* word  = (const float*)d_in[0];
    const int*   nbr   = (const int*)  d_in[1];
    const float* mask  = (const float*)d_in[2];
    const float* W_enc = (const float*)d_in[3];
    const float* b_enc = (const float*)d_in[4];
    const float* W2    = (const float*)d_in[5];
    float* out = (float*)d_out;

    unsigned short* wt      = (unsigned short*)d_ws;              // [2][128][128] bf16, 64 KB
    unsigned short* Xb      = wt + 2 * EMB * EMB;                 // [32768][128] bf16, 8 MB
    unsigned short* Yb      = Xb + (size_t)R_TOT * EMB;           // [32768][128] bf16, 8 MB
    float*          partial = (float*)(Yb + (size_t)R_TOT * EMB); // [64][16][4][128] f32, 2 MB

    prep_w     <<<16,         256, 0, stream>>>(W_enc, wt);
    dual_gemm  <<<R_TOT / 64, 256, 0, stream>>>(word, wt, b_enc, Xb, Yb);
    gather_pool<<<B_SZ * 16,  256, 0, stream>>>(Xb, Yb, nbr, mask, partial);
    final_mm   <<<B_SZ,       128, 0, stream>>>(partial, W2, out);
}

// Round 4
// 42.118 us; speedup vs baseline: 2.6125x; 1.0757x over previous
//
#include <hip/hip_runtime.h>
#include <hip/hip_bf16.h>

#define B_SZ  64
#define N_SZ  512
#define K_SZ  16
#define EMB   128
#define R_TOT (B_SZ * N_SZ)   // 32768 rows

typedef __attribute__((ext_vector_type(8))) short bf16x8;
typedef __attribute__((ext_vector_type(4))) float f32x4;

// XOR-swizzled u16 index into a [*][128]-u16 LDS tile (16B-unit granularity).
// Breaks the 256B-row-stride bank aliasing on ds_read_b128 fragment reads.
#define SWZ(row, col) ((((row) << 7)) + ((((col) >> 3) ^ ((row) & 15)) << 3) + ((col) & 7))

static __device__ __forceinline__ unsigned short f2bf(float x) {
    __hip_bfloat16 h = __float2bfloat16(x);   // RNE
    return *reinterpret_cast<unsigned short*>(&h);
}
static __device__ __forceinline__ float bf2f(unsigned short u) {
    union { unsigned int u32; float f; } c; c.u32 = ((unsigned int)u) << 16; return c.f;
}

// W_enc [256][128] f32 -> wt[2][128][128] bf16, transposed: wt[half][e][f] = W_enc[half*128+f][e]
__global__ __launch_bounds__(256) void prep_w(const float* __restrict__ W_enc,
                                              unsigned short* __restrict__ wt)
{
    __shared__ float s[16][128];
    const int tid = threadIdx.x;
    const int f0 = blockIdx.x * 16;          // 16 blocks cover 256 f-rows
    for (int i = tid; i < 2048; i += 256) {
        int r = i >> 7, c = i & 127;
        s[r][c] = W_enc[(f0 + r) * EMB + c];
    }
    __syncthreads();
    if (tid < 128) {
        const int e = tid;
        unsigned short* dst = wt + ((f0 >= 128) ? (EMB * EMB) : 0) + e * EMB + (f0 & 127);
        for (int j = 0; j < 16; j += 2) {
            unsigned int v = (unsigned int)f2bf(s[j][e]) | ((unsigned int)f2bf(s[j + 1][e]) << 16);
            *(unsigned int*)(dst + j) = v;
        }
    }
}

// Fused: X = word@Wtop + bias (store bf16, pre-relu); Y = relu(X)@Wbot (store bf16)
// block = 64 rows, 256 threads (4 waves). Wave w owns cols [w*32, w*32+32).
// LDS tiles are XOR-swizzled (SWZ) so MFMA fragment ds_read_b128 are conflict-free.
__global__ __launch_bounds__(256) void dual_gemm(const float* __restrict__ word,
                                                 const unsigned short* __restrict__ wt,
                                                 const float* __restrict__ bias,
                                                 unsigned short* __restrict__ Xb,
                                                 unsigned short* __restrict__ Yb)
{
    __shared__ unsigned short sA[64 * EMB];          // 16 KB, A-tile (bf16), swizzled
    __shared__ unsigned short sW[2 * EMB * EMB];     // 64 KB, both W halves, swizzled
    const int tid = threadIdx.x;
    const int block_row = blockIdx.x * 64;

    {   // stage both W halves: 4096 uint4; each uint4 = one 16B unit -> swizzled slot
        const uint4* src = (const uint4*)wt;
        for (int i = tid; i < 4096; i += 256) {
            int h = i >> 11, j = i & 2047;
            int e = j >> 4, u = j & 15;
            *(uint4*)&sW[(h << 14) + (e << 7) + ((u ^ (e & 15)) << 3)] = src[i];
        }
    }
    for (int i = tid; i < 2048; i += 256) {          // A tile f32 -> bf16
        int r = i >> 5, c4 = i & 31;                 // col = c4*4 (8B-aligned in-unit)
        float4 v = ((const float4*)(word + (size_t)(block_row + r) * EMB))[c4];
        unsigned short o[4] = { f2bf(v.x), f2bf(v.y), f2bf(v.z), f2bf(v.w) };
        *(uint2*)&sA[SWZ(r, c4 * 4)] = *(uint2*)o;
    }
    __syncthreads();

    const int lane  = tid & 63;
    const int w     = tid >> 6;
    const int l15   = lane & 15;
    const int g     = lane >> 4;                 // 0..3
    const int ncol0 = w * 32;

    f32x4 acc[4][2];
    #pragma unroll
    for (int mb = 0; mb < 4; ++mb)
        #pragma unroll
        for (int nb = 0; nb < 2; ++nb)
            acc[mb][nb] = (f32x4){0.f, 0.f, 0.f, 0.f};

    // ---- GEMM1: sA @ sW[0] ----
    #pragma unroll
    for (int ks = 0; ks < 4; ++ks) {
        bf16x8 a[4], b[2];
        #pragma unroll
        for (int mb = 0; mb < 4; ++mb)
            a[mb] = *(const bf16x8*)&sA[SWZ(mb * 16 + l15, ks * 32 + g * 8)];
        #pragma unroll
        for (int nb = 0; nb < 2; ++nb)
            b[nb] = *(const bf16x8*)&sW[SWZ(ncol0 + nb * 16 + l15, ks * 32 + g * 8)];
        #pragma unroll
        for (int mb = 0; mb < 4; ++mb)
            #pragma unroll
            for (int nb = 0; nb < 2; ++nb)
                acc[mb][nb] = __builtin_amdgcn_mfma_f32_16x16x32_bf16(a[mb], b[nb], acc[mb][nb], 0, 0, 0);
    }
    __syncthreads();   // everyone done READING sA before we overwrite it

    // epilogue 1: X = acc + bias; store Xb (pre-relu); relu into sA for GEMM2
    #pragma unroll
    for (int mb = 0; mb < 4; ++mb) {
        #pragma unroll
        for (int nb = 0; nb < 2; ++nb) {
            const int col = ncol0 + nb * 16 + l15;
            const float bv = bias[col];
            #pragma unroll
            for (int r = 0; r < 4; ++r) {
                const int row_l = mb * 16 + g * 4 + r;
                float x = acc[mb][nb][r] + bv;
                Xb[(size_t)(block_row + row_l) * EMB + col] = f2bf(x);
                sA[SWZ(row_l, col)] = f2bf(fmaxf(x, 0.f));
            }
            acc[mb][nb] = (f32x4){0.f, 0.f, 0.f, 0.f};
        }
    }
    __syncthreads();

    // ---- GEMM2: relu(X) @ sW[1] ----
    #pragma unroll
    for (int ks = 0; ks < 4; ++ks) {
        bf16x8 a[4], b[2];
        #pragma unroll
        for (int mb = 0; mb < 4; ++mb)
            a[mb] = *(const bf16x8*)&sA[SWZ(mb * 16 + l15, ks * 32 + g * 8)];
        #pragma unroll
        for (int nb = 0; nb < 2; ++nb)
            b[nb] = *(const bf16x8*)&sW[(1 << 14) + SWZ(ncol0 + nb * 16 + l15, ks * 32 + g * 8)];
        #pragma unroll
        for (int mb = 0; mb < 4; ++mb)
            #pragma unroll
            for (int nb = 0; nb < 2; ++nb)
                acc[mb][nb] = __builtin_amdgcn_mfma_f32_16x16x32_bf16(a[mb], b[nb], acc[mb][nb], 0, 0, 0);
    }
    #pragma unroll
    for (int mb = 0; mb < 4; ++mb)
        #pragma unroll
        for (int nb = 0; nb < 2; ++nb) {
            const int col = ncol0 + nb * 16 + l15;
            #pragma unroll
            for (int r = 0; r < 4; ++r) {
                const int row_l = mb * 16 + g * 4 + r;
                Yb[(size_t)(block_row + row_l) * EMB + col] = f2bf(acc[mb][nb][r]);
            }
        }
}

// partial[b][chunk][g][e] = sum over group-g's 8 n's of mask * relu(X + mean_k Y[nb])
// XCD swizzle: all 16 chunks of batch b land on XCD b&7.
__global__ __launch_bounds__(256) void gather_pool(const unsigned short* __restrict__ Xb,
                                                   const unsigned short* __restrict__ Yb,
                                                   const int*   __restrict__ nbr,
                                                   const float* __restrict__ mask,
                                                   float* __restrict__ partial)
{
    const int bid   = blockIdx.x;
    const int xcd   = bid & 7;
    const int rest  = bid >> 3;
    const int chunk = rest & 15;
    const int b     = (rest >> 4) * 8 + xcd;
    const int g     = threadIdx.x >> 6;        // 4 groups of 64 lanes
    const int lane  = threadIdx.x & 63;
    const int e0    = lane * 2;
    const unsigned short* Yb_b = Yb + (size_t)b * N_SZ * EMB;

    float s0 = 0.f, s1 = 0.f;
    for (int nn = 0; nn < 8; ++nn) {
        const int n = chunk * 32 + g * 8 + nn;
        const long base = (long)b * N_SZ + n;
        const int* idx = nbr + base * K_SZ;
        int id[K_SZ];
        #pragma unroll
        for (int k = 0; k < K_SZ; ++k) id[k] = idx[k];
        float a0 = 0.f, a1 = 0.f;
        #pragma unroll
        for (int k = 0; k < K_SZ; ++k) {
            unsigned int v = *(const unsigned int*)(Yb_b + (size_t)id[k] * EMB + e0);
            a0 += bf2f((unsigned short)v);
            a1 += bf2f((unsigned short)(v >> 16));
        }
        unsigned int xv = *(const unsigned int*)(Xb + base * EMB + e0);
        const float m = mask[base];
        s0 += fmaxf(bf2f((unsigned short)xv)         + a0 * 0.0625f, 0.f) * m;
        s1 += fmaxf(bf2f((unsigned short)(xv >> 16)) + a1 * 0.0625f, 0.f) * m;
    }
    // per-group slot: no cross-group race
    float2 o = { s0, s1 };
    *(float2*)&partial[(((size_t)b * 16 + chunk) * 4 + g) * EMB + e0] = o;
}

// out[b][e] = (sum over 64 partials of partial[b][c][:]) @ W2
__global__ __launch_bounds__(128) void final_mm(const float* __restrict__ partial,
                                                const float* __restrict__ W2,
                                                float* __restrict__ out)
{
    __shared__ float sp[EMB];
    const int b = blockIdx.x, e = threadIdx.x;
    float s = 0.f;
    #pragma unroll
    for (int c = 0; c < 64; ++c) s += partial[((size_t)b * 64 + c) * EMB + e];
    sp[e] = s;
    __syncthreads();
    float acc = 0.f;
    #pragma unroll 8
    for (int f = 0; f < EMB; ++f) acc += sp[f] * W2[f * EMB + e];
    out[b * EMB + e] = acc;
}

extern "C" void kernel_launch(void* const* d_in, const int* in_sizes, int n_in,
                              void* d_out, int out_size, void* d_ws, size_t ws_size,
                              hipStream_t stream)
{
    const float* word  = (const float*)d_in[0];
    const int*   nbr   = (const int*)  d_in[1];
    const float* mask  = (const float*)d_in[2];
    const float* W_enc = (const float*)d_in[3];
    const float* b_enc = (const float*)d_in[4];
    const float* W2    = (const float*)d_in[5];
    float* out = (float*)d_out;

    unsigned short* wt      = (unsigned short*)d_ws;              // [2][128][128] bf16, 64 KB
    unsigned short* Xb      = wt + 2 * EMB * EMB;                 // [32768][128] bf16, 8 MB
    unsigned short* Yb      = Xb + (size_t)R_TOT * EMB;           // [32768][128] bf16, 8 MB
    float*          partial = (float*)(Yb + (size_t)R_TOT * EMB); // [64][16][4][128] f32, 2 MB

    prep_w     <<<16,         256, 0, stream>>>(W_enc, wt);
    dual_gemm  <<<R_TOT / 64, 256, 0, stream>>>(word, wt, b_enc, Xb, Yb);
    gather_pool<<<B_SZ * 16,  256, 0, stream>>>(Xb, Yb, nbr, mask, partial);
    final_mm   <<<B_SZ,       128, 0, stream>>>(partial, W2, out);
}